// Round 4
// baseline (252.803 us; speedup 1.0000x reference)
//
#include <hip/hip_runtime.h>
#include <hip/hip_fp16.h>

namespace {

constexpr int B = 8, C = 64, H = 256, W = 256;
constexpr int HW = H * W;
constexpr int TP = 64;        // pixels per block in main kernel
constexpr int TSTRIDE = 68;   // LDS out-tile row stride (floats)
constexpr int LTS = 68;       // K1 LDS row stride in halfs (136B: 8B-aligned rows)

typedef float v4f __attribute__((ext_vector_type(4)));

// ---------- K1: x_enc [b,c,hw] f32  ->  ws [b,hw,c] f16 (streaming transpose) ----------
__global__ __launch_bounds__(256) void transpose_kernel(
    const float* __restrict__ x, __half* __restrict__ ws)
{
    __shared__ __half lt[256 * LTS];      // [hw_local][c], 34 KB
    const int t   = threadIdx.x;
    const int bid = blockIdx.x;           // B * HW/256 = 2048
    const int b   = bid >> 8;
    const int hw0 = (bid & 255) << 8;     // 256 hw positions per block
    const int wv  = t >> 6, lane = t & 63;

    // read coalesced (lane = hw, 256B/instr), scatter into LDS transposed
    for (int k = 0; k < 16; ++k) {
        const int c = wv * 16 + k;
        const float* __restrict__ src = x + (size_t)(b * C + c) * HW + hw0;
        #pragma unroll
        for (int q = 0; q < 4; ++q) {
            lt[(q * 64 + lane) * LTS + c] = __float2half(src[q * 64 + lane]);
        }
    }
    __syncthreads();

    // write ws rows: 8 lanes cover one 128B row -> fully coalesced 16B stores
    #pragma unroll
    for (int pass = 0; pass < 8; ++pass) {
        const int hw = pass * 32 + (t >> 3);
        const int c8 = (t & 7) * 8;
        const __half* __restrict__ row = &lt[hw * LTS + c8];  // 8B aligned
        const uint2 lo = *(const uint2*)(row);
        const uint2 hi = *(const uint2*)(row + 4);
        int4 v; v.x = (int)lo.x; v.y = (int)lo.y; v.z = (int)hi.x; v.w = (int)hi.y;
        *(int4*)(ws + ((size_t)b * HW + hw0 + hw) * 64 + c8) = v;  // keep in MALL (no NT)
    }
}

// ---------- K2: compute weights, gather from ws (coalesced), store out ----------
__global__ __launch_bounds__(256) void warp_main(
    const float* __restrict__ phi,
    const __half* __restrict__ ws,
    const float* __restrict__ mm,
    float* __restrict__ out)
{
    __shared__ float tile[64 * TSTRIDE];  // [c][p], zero-filled
    __shared__ float s_w[4][TP];
    __shared__ int   s_o[4][TP];
    __shared__ int   s_p[TP];
    __shared__ int   s_n;

    const int t   = threadIdx.x;
    const int bid = blockIdx.x;           // 8192
    const int wt  = bid & 3;
    const int h   = (bid >> 2) & (H - 1);
    const int b   = bid >> 10;
    const int w0  = wt * 64;

    {
        v4f z = {0.f, 0.f, 0.f, 0.f};
        for (int i = t; i < (64 * TSTRIDE) / 4; i += 256)
            *(v4f*)&tile[i * 4] = z;
    }

    if (t < 64) {
        const int lane = t;
        const int w    = w0 + lane;
        const int hw   = h * W + w;

        const float p0 = phi[(size_t)(b * 2 + 0) * HW + hw];
        const float p1 = phi[(size_t)(b * 2 + 1) * HW + hw];
        const float mv = mm[(size_t)b * HW + hw];

        const float gx = (2.0f * ((float)w + p0)) / (float)(W - 1) - 1.0f + 2.0f * p0;
        const float gy = (2.0f * ((float)h + p1)) / (float)(H - 1) - 1.0f + 2.0f * p1;
        const float ix = (gx + 1.0f) * (0.5f * (float)W) - 0.5f;
        const float iy = (gy + 1.0f) * (0.5f * (float)H) - 0.5f;

        const float x0f = floorf(ix);
        const float y0f = floorf(iy);
        const float fx1 = ix - x0f, fx0 = 1.0f - fx1;
        const float fy1 = iy - y0f, fy0 = 1.0f - fy1;

        const float wm1 = (float)(W - 1), hm1 = (float)(H - 1);
        const int x0 = (int)fminf(fmaxf(x0f,        0.0f), wm1);
        const int x1 = (int)fminf(fmaxf(x0f + 1.0f, 0.0f), wm1);
        const int y0 = (int)fminf(fmaxf(y0f,        0.0f), hm1);
        const int y1 = (int)fminf(fmaxf(y0f + 1.0f, 0.0f), hm1);

        const bool vx0 = (x0f >= 0.0f) && (x0f < (float)W);
        const bool vx1 = (x0f + 1.0f >= 0.0f) && (x0f + 1.0f < (float)W);
        const bool vy0 = (y0f >= 0.0f) && (y0f < (float)H);
        const bool vy1 = (y0f + 1.0f >= 0.0f) && (y0f + 1.0f < (float)H);

        const float w00 = fy0 * fx0 * ((vy0 && vx0) ? mv : 0.0f);
        const float w01 = fy0 * fx1 * ((vy0 && vx1) ? mv : 0.0f);
        const float w10 = fy1 * fx0 * ((vy1 && vx0) ? mv : 0.0f);
        const float w11 = fy1 * fx1 * ((vy1 && vx1) ? mv : 0.0f);

        const bool inb = (w00 + w01 + w10 + w11) != 0.0f;
        const unsigned long long mask = __ballot(inb);
        const int pos = __popcll(mask & ((1ULL << lane) - 1ULL));
        if (inb) {
            s_w[0][pos] = w00;  s_w[1][pos] = w01;
            s_w[2][pos] = w10;  s_w[3][pos] = w11;
            s_o[0][pos] = y0 * W + x0;
            s_o[1][pos] = y0 * W + x1;
            s_o[2][pos] = y1 * W + x0;
            s_o[3][pos] = y1 * W + x1;
            s_p[pos]    = lane;
        }
        if (lane == 0) s_n = __popcll(mask);
    }
    __syncthreads();

    // dense gathers from transposed fp16 ws: 128B coalesced per corner
    {
        const int wv   = t >> 6;
        const int lane = t & 63;   // channel
        const int n    = s_n;
        const __half* __restrict__ wsb = ws + (size_t)b * HW * 64 + lane;
        for (int i = wv; i < n; i += 4) {
            const float w00 = s_w[0][i], w01 = s_w[1][i];
            const float w10 = s_w[2][i], w11 = s_w[3][i];
            const float v = __half2float(wsb[(size_t)s_o[0][i] * 64]) * w00
                          + __half2float(wsb[(size_t)s_o[1][i] * 64]) * w01
                          + __half2float(wsb[(size_t)s_o[2][i] * 64]) * w10
                          + __half2float(wsb[(size_t)s_o[3][i] * 64]) * w11;
            tile[lane * TSTRIDE + s_p[i]] = v;
        }
    }
    __syncthreads();

    {
        const size_t obase = (size_t)b * C * HW + (size_t)h * W + w0;
        const int cl = t >> 4;
        const int p4 = (t & 15) * 4;
        #pragma unroll
        for (int pass = 0; pass < 4; ++pass) {
            const int c = pass * 16 + cl;
            v4f v = *(const v4f*)&tile[c * TSTRIDE + p4];
            __builtin_nontemporal_store(v, (v4f*)(out + obase + (size_t)c * HW + p4));
        }
    }
}

// ---------- fallback (round-3 single kernel) if ws is too small ----------
__global__ __launch_bounds__(256) void warp_fallback(
    const float* __restrict__ phi,
    const float* __restrict__ xenc,
    const float* __restrict__ mm,
    float* __restrict__ out)
{
    const int tid = blockIdx.x * 256 + threadIdx.x;
    const int w = tid & (W - 1);
    const int h = (tid >> 8) & (H - 1);
    const int b = tid >> 16;
    const int hw = h * W + w;

    const float p0 = phi[(size_t)(b * 2 + 0) * HW + hw];
    const float p1 = phi[(size_t)(b * 2 + 1) * HW + hw];
    const float mv = mm[(size_t)b * HW + hw];

    const float gx = (2.0f * ((float)w + p0)) / (float)(W - 1) - 1.0f + 2.0f * p0;
    const float gy = (2.0f * ((float)h + p1)) / (float)(H - 1) - 1.0f + 2.0f * p1;
    const float ix = (gx + 1.0f) * (0.5f * (float)W) - 0.5f;
    const float iy = (gy + 1.0f) * (0.5f * (float)H) - 0.5f;

    const float x0f = floorf(ix);
    const float y0f = floorf(iy);
    const float fx1 = ix - x0f, fx0 = 1.0f - fx1;
    const float fy1 = iy - y0f, fy0 = 1.0f - fy1;

    const float wm1 = (float)(W - 1), hm1 = (float)(H - 1);
    const int x0 = (int)fminf(fmaxf(x0f,        0.0f), wm1);
    const int x1 = (int)fminf(fmaxf(x0f + 1.0f, 0.0f), wm1);
    const int y0 = (int)fminf(fmaxf(y0f,        0.0f), hm1);
    const int y1 = (int)fminf(fmaxf(y0f + 1.0f, 0.0f), hm1);

    const bool vx0 = (x0f >= 0.0f) && (x0f < (float)W);
    const bool vx1 = (x0f + 1.0f >= 0.0f) && (x0f + 1.0f < (float)W);
    const bool vy0 = (y0f >= 0.0f) && (y0f < (float)H);
    const bool vy1 = (y0f + 1.0f >= 0.0f) && (y0f + 1.0f < (float)H);

    const float w00 = fy0 * fx0 * ((vy0 && vx0) ? mv : 0.0f);
    const float w01 = fy0 * fx1 * ((vy0 && vx1) ? mv : 0.0f);
    const float w10 = fy1 * fx0 * ((vy1 && vx0) ? mv : 0.0f);
    const float w11 = fy1 * fx1 * ((vy1 && vx1) ? mv : 0.0f);
    const bool doGather = (w00 + w01 + w10 + w11) != 0.0f;

    const int o00 = y0 * W + x0, o01 = y0 * W + x1;
    const int o10 = y1 * W + x0, o11 = y1 * W + x1;

    const float* __restrict__ xb = xenc + (size_t)b * C * HW;
    float* __restrict__ ob = out + (size_t)b * C * HW + hw;

    #pragma unroll 4
    for (int c = 0; c < C; ++c) {
        float v = 0.0f;
        if (doGather) {
            const float* __restrict__ xc = xb + (size_t)c * HW;
            v = xc[o00] * w00 + xc[o01] * w01 + xc[o10] * w10 + xc[o11] * w11;
        }
        ob[(size_t)c * HW] = v;
    }
}

}  // namespace

extern "C" void kernel_launch(void* const* d_in, const int* in_sizes, int n_in,
                              void* d_out, int out_size, void* d_ws, size_t ws_size,
                              hipStream_t stream) {
    const float* phi  = (const float*)d_in[0];
    const float* xenc = (const float*)d_in[1];
    const float* mm   = (const float*)d_in[2];
    float* out = (float*)d_out;

    const size_t need = (size_t)B * HW * C * sizeof(__half);  // 64 MiB
    if (ws_size >= need) {
        __half* ws = (__half*)d_ws;
        transpose_kernel<<<dim3(B * (HW / 256)), dim3(256), 0, stream>>>(xenc, ws);
        warp_main<<<dim3(B * H * (W / 64)), dim3(256), 0, stream>>>(phi, ws, mm, out);
    } else {
        warp_fallback<<<dim3((B * HW) / 256), dim3(256), 0, stream>>>(phi, xenc, mm, out);
    }
}

// Round 5
// 249.047 us; speedup vs baseline: 1.0151x; 1.0151x over previous
//
#include <hip/hip_runtime.h>
#include <hip/hip_fp16.h>

namespace {

constexpr int B = 8, C = 64, H = 256, W = 256;
constexpr int HW = H * W;
constexpr int R1 = 66;        // K1 LDS row stride in halfs (chosen: 2-way banks both phases)
constexpr int TS = 68;        // K2 LDS tile row stride (floats)

typedef float v4f __attribute__((ext_vector_type(4)));
typedef unsigned int v4u __attribute__((ext_vector_type(4)));

// ---------- K1: x_enc [b,c,hw] f32  ->  ws [b,hw,c] f16 ----------
// tile: 64 hw x 64 c per block; 8192 blocks
__global__ __launch_bounds__(256) void transpose_kernel(
    const float* __restrict__ x, __half* __restrict__ ws)
{
    __shared__ __half lt[64 * R1];        // [hw_local][c], 8448 B
    const int t  = threadIdx.x;
    const int wv = t >> 6, l = t & 63;
    const int bid = blockIdx.x;           // B * (HW/64) = 8192
    const int b   = bid >> 10;
    const int hw0 = (bid & 1023) << 6;

    const int a  = l & 15;                // hw quad index (0..15)
    const int cq = l >> 4;                // 0..3

    #pragma unroll
    for (int k = 0; k < 4; ++k) {
        const int c = wv * 16 + k * 4 + cq;
        const v4f v = __builtin_nontemporal_load(
            (const v4f*)(x + (size_t)(b * C + c) * HW + hw0 + a * 4));
        // transpose scatter: 4 scalar b16 writes, 2-way banks (free)
        lt[(a * 4 + 0) * R1 + c] = __float2half(v.x);
        lt[(a * 4 + 1) * R1 + c] = __float2half(v.y);
        lt[(a * 4 + 2) * R1 + c] = __float2half(v.z);
        lt[(a * 4 + 3) * R1 + c] = __float2half(v.w);
    }
    __syncthreads();

    // read rows [hw][c]: thread -> hw = wv*16 + (l>>2), 16 halfs at c0 = (l&3)*16
    const int hw = wv * 16 + (l >> 2);
    const int c0 = (l & 3) * 16;
    const unsigned int* __restrict__ row = (const unsigned int*)&lt[hw * R1 + c0];  // 4B aligned
    v4u lo, hi;
    lo.x = row[0]; lo.y = row[1]; lo.z = row[2]; lo.w = row[3];
    hi.x = row[4]; hi.y = row[5]; hi.z = row[6]; hi.w = row[7];
    __half* __restrict__ dst = ws + ((size_t)b * HW + hw0 + hw) * 64 + c0;  // 16B aligned
    *(v4u*)dst = lo;
    *((v4u*)dst + 1) = hi;
}

// ---------- K2: weights + coalesced gather from ws + masked store ----------
__global__ __launch_bounds__(256) void warp_main(
    const float* __restrict__ phi,
    const __half* __restrict__ ws,
    const float* __restrict__ mm,
    float* __restrict__ out)
{
    __shared__ float tile[64 * TS];       // [c][p] — NOT zero-filled; mask handles zeros
    __shared__ float s_w[4][64];
    __shared__ int   s_o[4][64];
    __shared__ int   s_p[64];
    __shared__ int   s_n;
    __shared__ unsigned long long s_mask;

    const int t   = threadIdx.x;
    const int bid = blockIdx.x;           // 8192
    const int wt  = bid & 3;
    const int h   = (bid >> 2) & (H - 1);
    const int b   = bid >> 10;
    const int w0  = wt * 64;

    if (t < 64) {                         // wave 0 only
        const int lane = t;
        const int w    = w0 + lane;
        const int hw   = h * W + w;

        const float p0 = phi[(size_t)(b * 2 + 0) * HW + hw];
        const float p1 = phi[(size_t)(b * 2 + 1) * HW + hw];
        const float mv = mm[(size_t)b * HW + hw];

        const float gx = (2.0f * ((float)w + p0)) / (float)(W - 1) - 1.0f + 2.0f * p0;
        const float gy = (2.0f * ((float)h + p1)) / (float)(H - 1) - 1.0f + 2.0f * p1;
        const float ix = (gx + 1.0f) * (0.5f * (float)W) - 0.5f;
        const float iy = (gy + 1.0f) * (0.5f * (float)H) - 0.5f;

        const float x0f = floorf(ix);
        const float y0f = floorf(iy);
        const float fx1 = ix - x0f, fx0 = 1.0f - fx1;
        const float fy1 = iy - y0f, fy0 = 1.0f - fy1;

        const float wm1 = (float)(W - 1), hm1 = (float)(H - 1);
        const int x0 = (int)fminf(fmaxf(x0f,        0.0f), wm1);
        const int x1 = (int)fminf(fmaxf(x0f + 1.0f, 0.0f), wm1);
        const int y0 = (int)fminf(fmaxf(y0f,        0.0f), hm1);
        const int y1 = (int)fminf(fmaxf(y0f + 1.0f, 0.0f), hm1);

        const bool vx0 = (x0f >= 0.0f) && (x0f < (float)W);
        const bool vx1 = (x0f + 1.0f >= 0.0f) && (x0f + 1.0f < (float)W);
        const bool vy0 = (y0f >= 0.0f) && (y0f < (float)H);
        const bool vy1 = (y0f + 1.0f >= 0.0f) && (y0f + 1.0f < (float)H);

        const float w00 = fy0 * fx0 * ((vy0 && vx0) ? mv : 0.0f);
        const float w01 = fy0 * fx1 * ((vy0 && vx1) ? mv : 0.0f);
        const float w10 = fy1 * fx0 * ((vy1 && vx0) ? mv : 0.0f);
        const float w11 = fy1 * fx1 * ((vy1 && vx1) ? mv : 0.0f);

        const bool inb = (w00 + w01 + w10 + w11) != 0.0f;
        const unsigned long long mask = __ballot(inb);
        const int pos = __popcll(mask & ((1ULL << lane) - 1ULL));
        if (inb) {
            s_w[0][pos] = w00;  s_w[1][pos] = w01;
            s_w[2][pos] = w10;  s_w[3][pos] = w11;
            s_o[0][pos] = y0 * W + x0;
            s_o[1][pos] = y0 * W + x1;
            s_o[2][pos] = y1 * W + x0;
            s_o[3][pos] = y1 * W + x1;
            s_p[pos]    = lane;
        }
        if (lane == 0) { s_n = __popcll(mask); s_mask = mask; }
    }
    __syncthreads();

    // dense gathers: one wave per in-bounds pixel, lane = channel, 128B coalesced
    {
        const int wv   = t >> 6;
        const int lane = t & 63;
        const int n    = s_n;
        const __half* __restrict__ wsb = ws + (size_t)b * HW * 64 + lane;
        for (int i = wv; i < n; i += 4) {
            const float w00 = s_w[0][i], w01 = s_w[1][i];
            const float w10 = s_w[2][i], w11 = s_w[3][i];
            const float v = __half2float(wsb[(size_t)s_o[0][i] * 64]) * w00
                          + __half2float(wsb[(size_t)s_o[1][i] * 64]) * w01
                          + __half2float(wsb[(size_t)s_o[2][i] * 64]) * w10
                          + __half2float(wsb[(size_t)s_o[3][i] * 64]) * w11;
            tile[lane * TS + s_p[i]] = v;
        }
    }
    __syncthreads();

    // masked store: invalid pixels -> 0 via cndmask (no tile zero-fill needed)
    {
        const unsigned long long msk = s_mask;
        const size_t obase = (size_t)b * C * HW + (size_t)h * W + w0;
        const int cl = t >> 4;
        const int p4 = (t & 15) * 4;
        #pragma unroll
        for (int pass = 0; pass < 4; ++pass) {
            const int c = pass * 16 + cl;
            v4f v = *(const v4f*)&tile[c * TS + p4];
            v.x = ((msk >> (p4 + 0)) & 1ULL) ? v.x : 0.0f;
            v.y = ((msk >> (p4 + 1)) & 1ULL) ? v.y : 0.0f;
            v.z = ((msk >> (p4 + 2)) & 1ULL) ? v.z : 0.0f;
            v.w = ((msk >> (p4 + 3)) & 1ULL) ? v.w : 0.0f;
            __builtin_nontemporal_store(v, (v4f*)(out + obase + (size_t)c * HW + p4));
        }
    }
}

// ---------- fallback if ws too small ----------
__global__ __launch_bounds__(256) void warp_fallback(
    const float* __restrict__ phi,
    const float* __restrict__ xenc,
    const float* __restrict__ mm,
    float* __restrict__ out)
{
    const int tid = blockIdx.x * 256 + threadIdx.x;
    const int w = tid & (W - 1);
    const int h = (tid >> 8) & (H - 1);
    const int b = tid >> 16;
    const int hw = h * W + w;

    const float p0 = phi[(size_t)(b * 2 + 0) * HW + hw];
    const float p1 = phi[(size_t)(b * 2 + 1) * HW + hw];
    const float mv = mm[(size_t)b * HW + hw];

    const float gx = (2.0f * ((float)w + p0)) / (float)(W - 1) - 1.0f + 2.0f * p0;
    const float gy = (2.0f * ((float)h + p1)) / (float)(H - 1) - 1.0f + 2.0f * p1;
    const float ix = (gx + 1.0f) * (0.5f * (float)W) - 0.5f;
    const float iy = (gy + 1.0f) * (0.5f * (float)H) - 0.5f;

    const float x0f = floorf(ix);
    const float y0f = floorf(iy);
    const float fx1 = ix - x0f, fx0 = 1.0f - fx1;
    const float fy1 = iy - y0f, fy0 = 1.0f - fy1;

    const float wm1 = (float)(W - 1), hm1 = (float)(H - 1);
    const int x0 = (int)fminf(fmaxf(x0f,        0.0f), wm1);
    const int x1 = (int)fminf(fmaxf(x0f + 1.0f, 0.0f), wm1);
    const int y0 = (int)fminf(fmaxf(y0f,        0.0f), hm1);
    const int y1 = (int)fminf(fmaxf(y0f + 1.0f, 0.0f), hm1);

    const bool vx0 = (x0f >= 0.0f) && (x0f < (float)W);
    const bool vx1 = (x0f + 1.0f >= 0.0f) && (x0f + 1.0f < (float)W);
    const bool vy0 = (y0f >= 0.0f) && (y0f < (float)H);
    const bool vy1 = (y0f + 1.0f >= 0.0f) && (y0f + 1.0f < (float)H);

    const float w00 = fy0 * fx0 * ((vy0 && vx0) ? mv : 0.0f);
    const float w01 = fy0 * fx1 * ((vy0 && vx1) ? mv : 0.0f);
    const float w10 = fy1 * fx0 * ((vy1 && vx0) ? mv : 0.0f);
    const float w11 = fy1 * fx1 * ((vy1 && vx1) ? mv : 0.0f);
    const bool doGather = (w00 + w01 + w10 + w11) != 0.0f;

    const int o00 = y0 * W + x0, o01 = y0 * W + x1;
    const int o10 = y1 * W + x0, o11 = y1 * W + x1;

    const float* __restrict__ xb = xenc + (size_t)b * C * HW;
    float* __restrict__ ob = out + (size_t)b * C * HW + hw;

    #pragma unroll 4
    for (int c = 0; c < C; ++c) {
        float v = 0.0f;
        if (doGather) {
            const float* __restrict__ xc = xb + (size_t)c * HW;
            v = xc[o00] * w00 + xc[o01] * w01 + xc[o10] * w10 + xc[o11] * w11;
        }
        ob[(size_t)c * HW] = v;
    }
}

}  // namespace

extern "C" void kernel_launch(void* const* d_in, const int* in_sizes, int n_in,
                              void* d_out, int out_size, void* d_ws, size_t ws_size,
                              hipStream_t stream) {
    const float* phi  = (const float*)d_in[0];
    const float* xenc = (const float*)d_in[1];
    const float* mm   = (const float*)d_in[2];
    float* out = (float*)d_out;

    const size_t need = (size_t)B * HW * C * sizeof(__half);  // 64 MiB
    if (ws_size >= need) {
        __half* ws = (__half*)d_ws;
        transpose_kernel<<<dim3(B * (HW / 64)), dim3(256), 0, stream>>>(xenc, ws);
        warp_main<<<dim3(B * H * (W / 64)), dim3(256), 0, stream>>>(phi, ws, mm, out);
    } else {
        warp_fallback<<<dim3((B * HW) / 256), dim3(256), 0, stream>>>(phi, xenc, mm, out);
    }
}

// Round 6
// 247.565 us; speedup vs baseline: 1.0212x; 1.0060x over previous
//
#include <hip/hip_runtime.h>
#include <hip/hip_fp16.h>

namespace {

constexpr int B = 8, C = 64, H = 256, W = 256;
constexpr int HW = H * W;
constexpr int R1 = 68;        // K1 LDS row stride in halfs (136B: all b64 ops 8B-aligned)
constexpr int TS = 68;        // K2 LDS tile row stride (floats)

typedef float v4f __attribute__((ext_vector_type(4)));
typedef unsigned int v4u __attribute__((ext_vector_type(4)));

union H4 { struct { __half2 lo, hi; } h; uint2 u; };

// ---------- K1: x_enc [b,c,hw] f32  ->  ws [b,hw,c] f16 ----------
// tile: 64 hw x 64 c per block; 8192 blocks
__global__ __launch_bounds__(256) void transpose_kernel(
    const float* __restrict__ x, __half* __restrict__ ws)
{
    __shared__ __align__(16) __half lt[64 * R1];   // 8704 B
    const int t  = threadIdx.x;
    const int wv = t >> 6, l = t & 63;
    const int bid = blockIdx.x;           // B * (HW/64) = 8192
    const int b   = bid >> 10;
    const int hw0 = (bid & 1023) << 6;

    const int a  = l & 15;                // hw quad index: hw = a*4+q
    const int cq = l >> 4;                // channel quad 0..3
    const int c4 = wv * 16 + cq * 4;      // 4 ADJACENT channels c4..c4+3

    v4f vv[4];
    #pragma unroll
    for (int k = 0; k < 4; ++k) {        // NT loads: don't pollute MALL (ws must stay)
        vv[k] = __builtin_nontemporal_load(
            (const v4f*)(x + (size_t)(b * C + c4 + k) * HW + hw0 + a * 4));
    }
    // repack: for each hw q, ushort4 of channels c4..c4+3 -> one ds_write_b64
    #pragma unroll
    for (int q = 0; q < 4; ++q) {
        H4 pk;
        pk.h.lo = __halves2half2(__float2half(vv[0][q]), __float2half(vv[1][q]));
        pk.h.hi = __halves2half2(__float2half(vv[2][q]), __float2half(vv[3][q]));
        *(uint2*)&lt[(a * 4 + q) * R1 + c4] = pk.u;
    }
    __syncthreads();

    // store: 2 passes; 8 lanes cover one full 128B ws row -> 16B/lane coalesced
    #pragma unroll
    for (int p = 0; p < 2; ++p) {
        const int hw = p * 32 + (t >> 3);
        const int c0 = (t & 7) * 8;
        const uint2 r0 = *(const uint2*)&lt[hw * R1 + c0];
        const uint2 r1 = *(const uint2*)&lt[hw * R1 + c0 + 4];
        v4u s; s.x = r0.x; s.y = r0.y; s.z = r1.x; s.w = r1.y;
        *(v4u*)(ws + ((size_t)b * HW + hw0 + hw) * 64 + c0) = s;
    }
}

// ---------- K2: weights + coalesced gather from ws + masked store ----------
__global__ __launch_bounds__(256) void warp_main(
    const float* __restrict__ phi,
    const __half* __restrict__ ws,
    const float* __restrict__ mm,
    float* __restrict__ out)
{
    __shared__ float tile[64 * TS];       // [c][p] — not zero-filled; mask handles zeros
    __shared__ float s_w[4][64];
    __shared__ int   s_o[4][64];
    __shared__ int   s_p[64];
    __shared__ int   s_n;
    __shared__ unsigned long long s_mask;

    const int t   = threadIdx.x;
    const int bid = blockIdx.x;           // 8192
    const int wt  = bid & 3;
    const int h   = (bid >> 2) & (H - 1);
    const int b   = bid >> 10;
    const int w0  = wt * 64;

    if (t < 64) {                         // wave 0 only
        const int lane = t;
        const int w    = w0 + lane;
        const int hw   = h * W + w;

        const float p0 = phi[(size_t)(b * 2 + 0) * HW + hw];
        const float p1 = phi[(size_t)(b * 2 + 1) * HW + hw];
        const float mv = mm[(size_t)b * HW + hw];

        const float gx = (2.0f * ((float)w + p0)) / (float)(W - 1) - 1.0f + 2.0f * p0;
        const float gy = (2.0f * ((float)h + p1)) / (float)(H - 1) - 1.0f + 2.0f * p1;
        const float ix = (gx + 1.0f) * (0.5f * (float)W) - 0.5f;
        const float iy = (gy + 1.0f) * (0.5f * (float)H) - 0.5f;

        const float x0f = floorf(ix);
        const float y0f = floorf(iy);
        const float fx1 = ix - x0f, fx0 = 1.0f - fx1;
        const float fy1 = iy - y0f, fy0 = 1.0f - fy1;

        const float wm1 = (float)(W - 1), hm1 = (float)(H - 1);
        const int x0 = (int)fminf(fmaxf(x0f,        0.0f), wm1);
        const int x1 = (int)fminf(fmaxf(x0f + 1.0f, 0.0f), wm1);
        const int y0 = (int)fminf(fmaxf(y0f,        0.0f), hm1);
        const int y1 = (int)fminf(fmaxf(y0f + 1.0f, 0.0f), hm1);

        const bool vx0 = (x0f >= 0.0f) && (x0f < (float)W);
        const bool vx1 = (x0f + 1.0f >= 0.0f) && (x0f + 1.0f < (float)W);
        const bool vy0 = (y0f >= 0.0f) && (y0f < (float)H);
        const bool vy1 = (y0f + 1.0f >= 0.0f) && (y0f + 1.0f < (float)H);

        const float w00 = fy0 * fx0 * ((vy0 && vx0) ? mv : 0.0f);
        const float w01 = fy0 * fx1 * ((vy0 && vx1) ? mv : 0.0f);
        const float w10 = fy1 * fx0 * ((vy1 && vx0) ? mv : 0.0f);
        const float w11 = fy1 * fx1 * ((vy1 && vx1) ? mv : 0.0f);

        const bool inb = (w00 + w01 + w10 + w11) != 0.0f;
        const unsigned long long mask = __ballot(inb);
        const int pos = __popcll(mask & ((1ULL << lane) - 1ULL));
        if (inb) {
            s_w[0][pos] = w00;  s_w[1][pos] = w01;
            s_w[2][pos] = w10;  s_w[3][pos] = w11;
            s_o[0][pos] = y0 * W + x0;
            s_o[1][pos] = y0 * W + x1;
            s_o[2][pos] = y1 * W + x0;
            s_o[3][pos] = y1 * W + x1;
            s_p[pos]    = lane;
        }
        if (lane == 0) { s_n = __popcll(mask); s_mask = mask; }
    }
    __syncthreads();

    // dense gathers: one wave per in-bounds pixel, lane = channel, 128B coalesced
    {
        const int wv   = t >> 6;
        const int lane = t & 63;
        const int n    = s_n;
        const __half* __restrict__ wsb = ws + (size_t)b * HW * 64 + lane;
        for (int i = wv; i < n; i += 4) {
            const float w00 = s_w[0][i], w01 = s_w[1][i];
            const float w10 = s_w[2][i], w11 = s_w[3][i];
            const float v = __half2float(wsb[(size_t)s_o[0][i] * 64]) * w00
                          + __half2float(wsb[(size_t)s_o[1][i] * 64]) * w01
                          + __half2float(wsb[(size_t)s_o[2][i] * 64]) * w10
                          + __half2float(wsb[(size_t)s_o[3][i] * 64]) * w11;
            tile[lane * TS + s_p[i]] = v;
        }
    }
    __syncthreads();

    // masked store: invalid pixels -> 0 via cndmask (no tile zero-fill needed)
    {
        const unsigned long long msk = s_mask;
        const size_t obase = (size_t)b * C * HW + (size_t)h * W + w0;
        const int cl = t >> 4;
        const int p4 = (t & 15) * 4;
        #pragma unroll
        for (int pass = 0; pass < 4; ++pass) {
            const int c = pass * 16 + cl;
            v4f v = *(const v4f*)&tile[c * TS + p4];
            v.x = ((msk >> (p4 + 0)) & 1ULL) ? v.x : 0.0f;
            v.y = ((msk >> (p4 + 1)) & 1ULL) ? v.y : 0.0f;
            v.z = ((msk >> (p4 + 2)) & 1ULL) ? v.z : 0.0f;
            v.w = ((msk >> (p4 + 3)) & 1ULL) ? v.w : 0.0f;
            __builtin_nontemporal_store(v, (v4f*)(out + obase + (size_t)c * HW + p4));
        }
    }
}

// ---------- fallback if ws too small ----------
__global__ __launch_bounds__(256) void warp_fallback(
    const float* __restrict__ phi,
    const float* __restrict__ xenc,
    const float* __restrict__ mm,
    float* __restrict__ out)
{
    const int tid = blockIdx.x * 256 + threadIdx.x;
    const int w = tid & (W - 1);
    const int h = (tid >> 8) & (H - 1);
    const int b = tid >> 16;
    const int hw = h * W + w;

    const float p0 = phi[(size_t)(b * 2 + 0) * HW + hw];
    const float p1 = phi[(size_t)(b * 2 + 1) * HW + hw];
    const float mv = mm[(size_t)b * HW + hw];

    const float gx = (2.0f * ((float)w + p0)) / (float)(W - 1) - 1.0f + 2.0f * p0;
    const float gy = (2.0f * ((float)h + p1)) / (float)(H - 1) - 1.0f + 2.0f * p1;
    const float ix = (gx + 1.0f) * (0.5f * (float)W) - 0.5f;
    const float iy = (gy + 1.0f) * (0.5f * (float)H) - 0.5f;

    const float x0f = floorf(ix);
    const float y0f = floorf(iy);
    const float fx1 = ix - x0f, fx0 = 1.0f - fx1;
    const float fy1 = iy - y0f, fy0 = 1.0f - fy1;

    const float wm1 = (float)(W - 1), hm1 = (float)(H - 1);
    const int x0 = (int)fminf(fmaxf(x0f,        0.0f), wm1);
    const int x1 = (int)fminf(fmaxf(x0f + 1.0f, 0.0f), wm1);
    const int y0 = (int)fminf(fmaxf(y0f,        0.0f), hm1);
    const int y1 = (int)fminf(fmaxf(y0f + 1.0f, 0.0f), hm1);

    const bool vx0 = (x0f >= 0.0f) && (x0f < (float)W);
    const bool vx1 = (x0f + 1.0f >= 0.0f) && (x0f + 1.0f < (float)W);
    const bool vy0 = (y0f >= 0.0f) && (y0f < (float)H);
    const bool vy1 = (y0f + 1.0f >= 0.0f) && (y0f + 1.0f < (float)H);

    const float w00 = fy0 * fx0 * ((vy0 && vx0) ? mv : 0.0f);
    const float w01 = fy0 * fx1 * ((vy0 && vx1) ? mv : 0.0f);
    const float w10 = fy1 * fx0 * ((vy1 && vx0) ? mv : 0.0f);
    const float w11 = fy1 * fx1 * ((vy1 && vx1) ? mv : 0.0f);
    const bool doGather = (w00 + w01 + w10 + w11) != 0.0f;

    const int o00 = y0 * W + x0, o01 = y0 * W + x1;
    const int o10 = y1 * W + x0, o11 = y1 * W + x1;

    const float* __restrict__ xb = xenc + (size_t)b * C * HW;
    float* __restrict__ ob = out + (size_t)b * C * HW + hw;

    #pragma unroll 4
    for (int c = 0; c < C; ++c) {
        float v = 0.0f;
        if (doGather) {
            const float* __restrict__ xc = xb + (size_t)c * HW;
            v = xc[o00] * w00 + xc[o01] * w01 + xc[o10] * w10 + xc[o11] * w11;
        }
        ob[(size_t)c * HW] = v;
    }
}

}  // namespace

extern "C" void kernel_launch(void* const* d_in, const int* in_sizes, int n_in,
                              void* d_out, int out_size, void* d_ws, size_t ws_size,
                              hipStream_t stream) {
    const float* phi  = (const float*)d_in[0];
    const float* xenc = (const float*)d_in[1];
    const float* mm   = (const float*)d_in[2];
    float* out = (float*)d_out;

    const size_t need = (size_t)B * HW * C * sizeof(__half);  // 64 MiB
    if (ws_size >= need) {
        __half* ws = (__half*)d_ws;
        transpose_kernel<<<dim3(B * (HW / 64)), dim3(256), 0, stream>>>(xenc, ws);
        warp_main<<<dim3(B * H * (W / 64)), dim3(256), 0, stream>>>(phi, ws, mm, out);
    } else {
        warp_fallback<<<dim3((B * HW) / 256), dim3(256), 0, stream>>>(phi, xenc, mm, out);
    }
}